// Round 1
// baseline (293.910 us; speedup 1.0000x reference)
//
#include <hip/hip_runtime.h>
#include <math.h>

// ---------------- workspace layout (bytes) ----------------
#define O_CNT    (0)
#define O_FILL   (256*1024)
#define O_ROWPTR (512*1024)
#define O_DINV   (768*1024)
#define O_SMALL  (1024*1024)
#define O_COL    (1280*1024)          // E ints = 3.2 MB (space to 5 MB)
#define O_PART   (5*1024*1024)        // 12500*132*4 = 6.6 MB (space to 13 MB)
#define O_H1     (13*1024*1024)       // N*128 floats = 25.6 MB
// small[] float indices:
//   [0..127]   w2qk      [128] bias (bq.k + b2.wqk)
//   [132..259] S         [260] R
//   [264..391] new_trainOT

// ---------------- CSR build ----------------
__global__ void k_count(const int* __restrict__ dst, int* __restrict__ cnt, int E) {
    int e = blockIdx.x * blockDim.x + threadIdx.x;
    if (e < E) atomicAdd(&cnt[dst[e]], 1);
}

__global__ void k_dinv(const int* __restrict__ cnt, float* __restrict__ dinv, int N) {
    int i = blockIdx.x * blockDim.x + threadIdx.x;
    if (i < N) dinv[i] = rsqrtf((float)(cnt[i] + 1));   // +1 self-loop
}

// single-block scan: 1024 threads x 8 elems/thread per chunk
__global__ void k_scan(const int* __restrict__ cnt, int* __restrict__ row_ptr, int N) {
    __shared__ int wsum[16];
    __shared__ int carry_s;
    __shared__ int tot_s;
    int t = threadIdx.x, lane = t & 63, wid = t >> 6;
    if (t == 0) { carry_s = 0; row_ptr[0] = 0; }
    __syncthreads();
    const int PER = 8, CHUNK = 1024 * PER;
    for (int base = 0; base < N; base += CHUNK) {
        int i0 = base + t * PER;
        int v[PER]; int s8 = 0;
#pragma unroll
        for (int k = 0; k < PER; ++k) { int i = i0 + k; v[k] = (i < N) ? cnt[i] : 0; s8 += v[k]; }
        int incl = s8;
#pragma unroll
        for (int off = 1; off < 64; off <<= 1) {
            int n2 = __shfl_up(incl, off);
            if (lane >= off) incl += n2;
        }
        if (lane == 63) wsum[wid] = incl;
        __syncthreads();
        if (wid == 0) {
            int wv = (lane < 16) ? wsum[lane] : 0;
            int wincl = wv;
#pragma unroll
            for (int off = 1; off < 16; off <<= 1) {
                int n2 = __shfl_up(wincl, off);
                if (lane >= off) wincl += n2;
            }
            if (lane < 16) wsum[lane] = wincl - wv;   // exclusive
            if (lane == 15) tot_s = wincl;            // chunk total
        }
        __syncthreads();
        int run = carry_s + wsum[wid] + (incl - s8);
#pragma unroll
        for (int k = 0; k < PER; ++k) { int i = i0 + k; run += v[k]; if (i < N) row_ptr[i + 1] = run; }
        __syncthreads();
        if (t == 0) carry_s += tot_s;
        __syncthreads();
    }
}

__global__ void k_fill(const int* __restrict__ src, const int* __restrict__ dst,
                       const int* __restrict__ row_ptr, int* __restrict__ fill,
                       int* __restrict__ col, int E) {
    int e = blockIdx.x * blockDim.x + threadIdx.x;
    if (e < E) {
        int d = dst[e];
        int p = row_ptr[d] + atomicAdd(&fill[d], 1);
        col[p] = src[e];
    }
}

// ---------------- tiny precompute: w2qk / bias ----------------
__global__ void k_tiny1(const float* __restrict__ trainOT, const float* __restrict__ Wq,
                        const float* __restrict__ bq, const float* __restrict__ Wk,
                        const float* __restrict__ bk, const float* __restrict__ W2,
                        const float* __restrict__ b2, float* __restrict__ small) {
    __shared__ float kv[64];
    __shared__ float wqk[128];
    __shared__ float red[128];
    int t = threadIdx.x;   // 128 threads
    if (t < 64) {
        float acc = bk[t];
        for (int j = 0; j < 128; ++j) acc += trainOT[j] * Wk[j * 64 + t];
        kv[t] = acc;
    }
    __syncthreads();
    float accq = 0.f;
    for (int c = 0; c < 64; ++c) accq += Wq[t * 64 + c] * kv[c];
    wqk[t] = accq;
    red[t] = (t < 64) ? bq[t] * kv[t] : 0.f;
    __syncthreads();
    for (int off = 64; off >= 1; off >>= 1) { if (t < off) red[t] += red[t + off]; __syncthreads(); }
    float bqs = red[0];
    __syncthreads();
    float acc2 = 0.f;
    for (int j = 0; j < 128; ++j) acc2 += W2[t * 128 + j] * wqk[j];
    small[t] = acc2;                       // w2qk
    red[t] = b2[t] * wqk[t];
    __syncthreads();
    for (int off = 64; off >= 1; off >>= 1) { if (t < off) red[t] += red[t + off]; __syncthreads(); }
    if (t == 0) small[128] = bqs + red[0]; // bias
}

// ---------------- layer 1: Agg(x) then @W1 + b1, relu ----------------
__global__ void k_layer1(const float* __restrict__ x, const int* __restrict__ row_ptr,
                         const int* __restrict__ col, const float* __restrict__ dinv,
                         const float* __restrict__ W1, const float* __restrict__ b1,
                         float* __restrict__ h1, int N) {
    int gid = blockIdx.x * blockDim.x + threadIdx.x;
    int node = gid >> 6, lane = gid & 63;
    if (node >= N) return;
    float di = dinv[node];
    int s = row_ptr[node], e = row_ptr[node + 1];
    float a0 = 0.f, a1 = 0.f, a2 = 0.f;
    for (int j = s + lane; j < e; j += 64) {
        int u = col[j];
        float du = dinv[u];
        a0 += x[u * 3] * du; a1 += x[u * 3 + 1] * du; a2 += x[u * 3 + 2] * du;
    }
    if (lane == 0) { a0 += x[node * 3] * di; a1 += x[node * 3 + 1] * di; a2 += x[node * 3 + 2] * di; }
#pragma unroll
    for (int off = 32; off; off >>= 1) {
        a0 += __shfl_xor(a0, off);
        a1 += __shfl_xor(a1, off);
        a2 += __shfl_xor(a2, off);
    }
    a0 *= di; a1 *= di; a2 *= di;
    int c0 = lane, c1 = lane + 64;
    float v0 = a0 * W1[c0] + a1 * W1[128 + c0] + a2 * W1[256 + c0] + b1[c0];
    float v1 = a0 * W1[c1] + a1 * W1[128 + c1] + a2 * W1[256 + c1] + b1[c1];
    h1[node * 128 + c0] = fmaxf(v0, 0.f);
    h1[node * 128 + c1] = fmaxf(v1, 0.f);
}

// ---------------- layer 2 fused: g = Agg(h1); rel; S += rel*g; R += rel ----------------
__global__ void k_layer2(const float* __restrict__ h1, const int* __restrict__ row_ptr,
                         const int* __restrict__ col, const float* __restrict__ dinv,
                         const float* __restrict__ small, float* __restrict__ part, int N) {
    __shared__ float sS[4][128];
    __shared__ float sRw[4];
    int t = threadIdx.x, lane = t & 63, wid = t >> 6;
    int node = blockIdx.x * 4 + wid;
    float a0 = 0.f, a1 = 0.f, relv = 0.f;
    if (node < N) {
        float di = dinv[node];
        int s = row_ptr[node], e = row_ptr[node + 1];
        a0 = h1[node * 128 + lane] * di;          // self term
        a1 = h1[node * 128 + 64 + lane] * di;
        for (int j = s; j < e; ++j) {
            int u = col[j];
            float du = dinv[u];
            a0 += h1[u * 128 + lane] * du;
            a1 += h1[u * 128 + 64 + lane] * du;
        }
        a0 *= di; a1 *= di;                       // g[node][lane], g[node][lane+64]
        float dv = a0 * small[lane] + a1 * small[64 + lane];
#pragma unroll
        for (int off = 32; off; off >>= 1) dv += __shfl_xor(dv, off);
        float z = (dv + small[128]) * 0.125f;     // / sqrt(64)
        relv = 1.f / (1.f + expf(-z));
    }
    sS[wid][lane] = relv * a0;
    sS[wid][64 + lane] = relv * a1;
    if (lane == 0) sRw[wid] = relv;
    __syncthreads();
    if (t < 128) part[blockIdx.x * 132 + t] = sS[0][t] + sS[1][t] + sS[2][t] + sS[3][t];
    if (t == 128) part[blockIdx.x * 132 + 128] = sRw[0] + sRw[1] + sRw[2] + sRw[3];
}

__global__ void k_reduce_part(const float* __restrict__ part, int nblocks, float* __restrict__ small) {
    int c = blockIdx.x;   // 0..128 (128 == R)
    float acc = 0.f;
    for (int b = threadIdx.x; b < nblocks; b += blockDim.x) acc += part[b * 132 + c];
    __shared__ float sd[256];
    sd[threadIdx.x] = acc; __syncthreads();
    for (int off = 128; off; off >>= 1) { if (threadIdx.x < off) sd[threadIdx.x] += sd[threadIdx.x + off]; __syncthreads(); }
    if (threadIdx.x == 0) small[132 + c] = sd[0];
}

// ---------------- tail: newT = trainOT + (S@W2 + R*b2)@Wv + R*bv ----------------
__global__ void k_tiny2(const float* __restrict__ trainOT, const float* __restrict__ W2,
                        const float* __restrict__ b2, const float* __restrict__ Wv,
                        const float* __restrict__ bv, float* __restrict__ small,
                        float* __restrict__ out_tail) {
    __shared__ float t1[128];
    int t = threadIdx.x;   // 128
    float R = small[260];
    float acc = R * b2[t];
    for (int j = 0; j < 128; ++j) acc += small[132 + j] * W2[j * 128 + t];
    t1[t] = acc; __syncthreads();
    float acc2 = R * bv[t];
    for (int j = 0; j < 128; ++j) acc2 += t1[j] * Wv[j * 128 + t];
    float nt = trainOT[t] + acc2;
    small[264 + t] = nt;
    out_tail[t] = nt;
}

// ---------------- speak = newT @ Ws + bs ----------------
__global__ void k_speak(const float* __restrict__ Ws, const float* __restrict__ bs,
                        const float* __restrict__ small, float* __restrict__ out, int out_n) {
    __shared__ float nt[128];
    int t = threadIdx.x;
    if (t < 128) nt[t] = small[264 + t];
    __syncthreads();
    int j = (blockIdx.x * blockDim.x + t) * 2;
    if (j >= out_n) return;
    float2 b = *reinterpret_cast<const float2*>(bs + j);
    float acc0 = b.x, acc1 = b.y;
    for (int k = 0; k < 128; ++k) {
        float w = nt[k];
        float2 r = *reinterpret_cast<const float2*>(Ws + (size_t)k * out_n + j);
        acc0 += w * r.x; acc1 += w * r.y;
    }
    out[j] = acc0; out[j + 1] = acc1;
}

extern "C" void kernel_launch(void* const* d_in, const int* in_sizes, int n_in,
                              void* d_out, int out_size, void* d_ws, size_t ws_size,
                              hipStream_t stream) {
    const float* features = (const float*)d_in[0];
    const int*   eidx     = (const int*)d_in[1];
    const float* trainOT  = (const float*)d_in[2];
    const float* W1 = (const float*)d_in[3];
    const float* b1 = (const float*)d_in[4];
    const float* W2 = (const float*)d_in[5];
    const float* b2 = (const float*)d_in[6];
    const float* Wq = (const float*)d_in[7];
    const float* bq = (const float*)d_in[8];
    const float* Wk = (const float*)d_in[9];
    const float* bk = (const float*)d_in[10];
    const float* Wv = (const float*)d_in[11];
    const float* bv = (const float*)d_in[12];
    const float* Ws = (const float*)d_in[13];
    const float* bs = (const float*)d_in[14];

    int N = in_sizes[0] / 3;
    int E = in_sizes[1] / 2;
    const int* esrc = eidx;
    const int* edst = eidx + E;

    char* ws = (char*)d_ws;
    int*   cnt     = (int*)(ws + O_CNT);
    int*   fill    = (int*)(ws + O_FILL);
    int*   row_ptr = (int*)(ws + O_ROWPTR);
    float* dinv    = (float*)(ws + O_DINV);
    float* small   = (float*)(ws + O_SMALL);
    int*   col     = (int*)(ws + O_COL);
    float* part    = (float*)(ws + O_PART);
    float* h1      = (float*)(ws + O_H1);
    float* out     = (float*)d_out;
    int out_n = out_size - 128;

    hipMemsetAsync(cnt, 0, N * sizeof(int), stream);
    hipMemsetAsync(fill, 0, N * sizeof(int), stream);

    k_count<<<(E + 255) / 256, 256, 0, stream>>>(edst, cnt, E);
    k_dinv<<<(N + 255) / 256, 256, 0, stream>>>(cnt, dinv, N);
    k_scan<<<1, 1024, 0, stream>>>(cnt, row_ptr, N);
    k_fill<<<(E + 255) / 256, 256, 0, stream>>>(esrc, edst, row_ptr, fill, col, E);
    k_tiny1<<<1, 128, 0, stream>>>(trainOT, Wq, bq, Wk, bk, W2, b2, small);
    k_layer1<<<(N + 3) / 4, 256, 0, stream>>>(features, row_ptr, col, dinv, W1, b1, h1, N);
    int nb2 = (N + 3) / 4;
    k_layer2<<<nb2, 256, 0, stream>>>(h1, row_ptr, col, dinv, small, part, N);
    k_reduce_part<<<129, 256, 0, stream>>>(part, nb2, small);
    k_tiny2<<<1, 128, 0, stream>>>(trainOT, W2, b2, Wv, bv, small, out + out_n);
    k_speak<<<(out_n / 2 + 255) / 256, 256, 0, stream>>>(Ws, bs, small, out, out_n);
}

// Round 2
// 248.163 us; speedup vs baseline: 1.1843x; 1.1843x over previous
//
#include <hip/hip_runtime.h>
#include <math.h>

// ---------------- workspace layout (bytes) ----------------
#define O_CNT    (0)
#define O_FILL   (256*1024)
#define O_ROWPTR (512*1024)
#define O_DINV   (768*1024)
#define O_SMALL  (1024*1024)
#define O_XS     (1280*1024)          // N*3 floats = 600KB (to 1.9MB)
#define O_COL    (2*1024*1024)        // E ints = 3.2MB (to 5.2MB)
#define O_PART   (5504*1024)          // 2048*132*4 = 1.08MB (to 6.6MB)
#define O_H1     (7*1024*1024)        // N*64 uints (bf16x2) = 12.8MB
// small[] float indices:
//   [0..127]   w2qk      [128] bias (bq.k + b2.wqk)
//   [132..259] S         [260] R
//   [264..391] new_trainOT

#define LAYER2_BLOCKS 2048

static __device__ __forceinline__ unsigned int f2bf(float f) {
    unsigned int u = __float_as_uint(f);
    return (u + 0x7fffu + ((u >> 16) & 1u)) >> 16;            // RNE
}
static __device__ __forceinline__ float bf_lo(unsigned int w) { return __uint_as_float(w << 16); }
static __device__ __forceinline__ float bf_hi(unsigned int w) { return __uint_as_float(w & 0xffff0000u); }

// ---------------- CSR build ----------------
__global__ void k_count(const int* __restrict__ dst, int* __restrict__ cnt, int E) {
    int e = blockIdx.x * blockDim.x + threadIdx.x;
    if (e < E) atomicAdd(&cnt[dst[e]], 1);
}

// dinv + pre-scaled features xs = x * dinv
__global__ void k_prep(const int* __restrict__ cnt, const float* __restrict__ x,
                       float* __restrict__ dinv, float* __restrict__ xs, int N) {
    int i = blockIdx.x * blockDim.x + threadIdx.x;
    if (i < N) {
        float d = rsqrtf((float)(cnt[i] + 1));   // +1 self-loop
        dinv[i] = d;
        xs[i * 3]     = x[i * 3] * d;
        xs[i * 3 + 1] = x[i * 3 + 1] * d;
        xs[i * 3 + 2] = x[i * 3 + 2] * d;
    }
}

// single-block scan: 1024 threads x 8 elems/thread per chunk
__global__ void k_scan(const int* __restrict__ cnt, int* __restrict__ row_ptr, int N) {
    __shared__ int wsum[16];
    __shared__ int carry_s;
    __shared__ int tot_s;
    int t = threadIdx.x, lane = t & 63, wid = t >> 6;
    if (t == 0) { carry_s = 0; row_ptr[0] = 0; }
    __syncthreads();
    const int PER = 8, CHUNK = 1024 * PER;
    for (int base = 0; base < N; base += CHUNK) {
        int i0 = base + t * PER;
        int v[PER]; int s8 = 0;
#pragma unroll
        for (int k = 0; k < PER; ++k) { int i = i0 + k; v[k] = (i < N) ? cnt[i] : 0; s8 += v[k]; }
        int incl = s8;
#pragma unroll
        for (int off = 1; off < 64; off <<= 1) {
            int n2 = __shfl_up(incl, off);
            if (lane >= off) incl += n2;
        }
        if (lane == 63) wsum[wid] = incl;
        __syncthreads();
        if (wid == 0) {
            int wv = (lane < 16) ? wsum[lane] : 0;
            int wincl = wv;
#pragma unroll
            for (int off = 1; off < 16; off <<= 1) {
                int n2 = __shfl_up(wincl, off);
                if (lane >= off) wincl += n2;
            }
            if (lane < 16) wsum[lane] = wincl - wv;   // exclusive
            if (lane == 15) tot_s = wincl;            // chunk total
        }
        __syncthreads();
        int run = carry_s + wsum[wid] + (incl - s8);
#pragma unroll
        for (int k = 0; k < PER; ++k) { int i = i0 + k; run += v[k]; if (i < N) row_ptr[i + 1] = run; }
        __syncthreads();
        if (t == 0) carry_s += tot_s;
        __syncthreads();
    }
}

__global__ void k_fill(const int* __restrict__ src, const int* __restrict__ dst,
                       const int* __restrict__ row_ptr, int* __restrict__ fill,
                       int* __restrict__ col, int E) {
    int e = blockIdx.x * blockDim.x + threadIdx.x;
    if (e < E) {
        int d = dst[e];
        int p = row_ptr[d] + atomicAdd(&fill[d], 1);
        col[p] = src[e];
    }
}

// ---------------- tiny precompute: w2qk / bias ----------------
__global__ void k_tiny1(const float* __restrict__ trainOT, const float* __restrict__ Wq,
                        const float* __restrict__ bq, const float* __restrict__ Wk,
                        const float* __restrict__ bk, const float* __restrict__ W2,
                        const float* __restrict__ b2, float* __restrict__ small) {
    __shared__ float kv[64];
    __shared__ float wqk[128];
    __shared__ float red[128];
    int t = threadIdx.x;   // 128 threads
    if (t < 64) {
        float acc = bk[t];
        for (int j = 0; j < 128; ++j) acc += trainOT[j] * Wk[j * 64 + t];
        kv[t] = acc;
    }
    __syncthreads();
    float accq = 0.f;
    for (int c = 0; c < 64; ++c) accq += Wq[t * 64 + c] * kv[c];
    wqk[t] = accq;
    red[t] = (t < 64) ? bq[t] * kv[t] : 0.f;
    __syncthreads();
    for (int off = 64; off >= 1; off >>= 1) { if (t < off) red[t] += red[t + off]; __syncthreads(); }
    float bqs = red[0];
    __syncthreads();
    float acc2 = 0.f;
    for (int j = 0; j < 128; ++j) acc2 += W2[t * 128 + j] * wqk[j];
    small[t] = acc2;                       // w2qk
    red[t] = b2[t] * wqk[t];
    __syncthreads();
    for (int off = 64; off >= 1; off >>= 1) { if (t < off) red[t] += red[t + off]; __syncthreads(); }
    if (t == 0) small[128] = bqs + red[0]; // bias
}

// ---------------- layer 1: Agg(xs) then @W1 + b1, relu, *dinv, pack bf16x2 ----------------
__global__ void k_layer1(const float* __restrict__ xs, const int* __restrict__ row_ptr,
                         const int* __restrict__ col, const float* __restrict__ dinv,
                         const float* __restrict__ W1, const float* __restrict__ b1,
                         unsigned int* __restrict__ h1s, int N) {
    int gid = blockIdx.x * blockDim.x + threadIdx.x;
    int node = gid >> 6, lane = gid & 63;
    if (node >= N) return;
    float di = dinv[node];
    int s = row_ptr[node], e = row_ptr[node + 1];
    float a0 = 0.f, a1 = 0.f, a2 = 0.f;
    for (int j = s + lane; j < e; j += 64) {
        int u = col[j];
        a0 += xs[u * 3]; a1 += xs[u * 3 + 1]; a2 += xs[u * 3 + 2];
    }
    if (lane == 0) { a0 += xs[node * 3]; a1 += xs[node * 3 + 1]; a2 += xs[node * 3 + 2]; }
#pragma unroll
    for (int off = 32; off; off >>= 1) {
        a0 += __shfl_xor(a0, off);
        a1 += __shfl_xor(a1, off);
        a2 += __shfl_xor(a2, off);
    }
    a0 *= di; a1 *= di; a2 *= di;
    int c = 2 * lane;
    // store relu(h1)*dinv[node] packed as 2x bf16 (cols 2*lane, 2*lane+1)
    float v0 = fmaxf(a0 * W1[c]     + a1 * W1[128 + c]     + a2 * W1[256 + c]     + b1[c],     0.f) * di;
    float v1 = fmaxf(a0 * W1[c + 1] + a1 * W1[128 + c + 1] + a2 * W1[256 + c + 1] + b1[c + 1], 0.f) * di;
    h1s[node * 64 + lane] = f2bf(v0) | (f2bf(v1) << 16);
}

// ---------------- layer 2 fused: g = Agg(h1s)*di; rel; S += rel*g; R += rel ----------------
// grid-stride waves, register S accumulators, one partial per block
__global__ void k_layer2(const unsigned int* __restrict__ h1s, const int* __restrict__ row_ptr,
                         const int* __restrict__ col, const float* __restrict__ dinv,
                         const float* __restrict__ small, float* __restrict__ part, int N) {
    int t = threadIdx.x, lane = t & 63, wid = t >> 6;
    int wg = blockIdx.x * 4 + wid;
    const int nwaves = LAYER2_BLOCKS * 4;
    float w0 = small[2 * lane], w1 = small[2 * lane + 1], bias = small[128];
    float sa0 = 0.f, sa1 = 0.f, sR = 0.f;
    for (int node = wg; node < N; node += nwaves) {
        float di = dinv[node];
        int s = row_ptr[node], e = row_ptr[node + 1];
        unsigned int selfw = h1s[node * 64 + lane];
        float a0 = bf_lo(selfw), a1 = bf_hi(selfw);
        for (int base = s; base < e; base += 64) {
            int myu = (base + lane < e) ? col[base + lane] : 0;
            int cnt2 = min(64, e - base);
#pragma unroll 4
            for (int k = 0; k < cnt2; ++k) {
                int u = __builtin_amdgcn_readlane(myu, k);   // wave-uniform -> SGPR base
                unsigned int w = h1s[u * 64 + lane];
                a0 += bf_lo(w); a1 += bf_hi(w);
            }
        }
        a0 *= di; a1 *= di;                       // g[node][2*lane], g[node][2*lane+1]
        float dv = a0 * w0 + a1 * w1;
#pragma unroll
        for (int off = 32; off; off >>= 1) dv += __shfl_xor(dv, off);
        float z = (dv + bias) * 0.125f;           // / sqrt(64)
        float rel = 1.f / (1.f + __expf(-z));
        sa0 += rel * a0; sa1 += rel * a1; sR += rel;
    }
    __shared__ float sS[4][130];
    sS[wid][2 * lane] = sa0;
    sS[wid][2 * lane + 1] = sa1;
    if (lane == 0) sS[wid][128] = sR;
    __syncthreads();
    if (t < 129) part[blockIdx.x * 132 + t] = sS[0][t] + sS[1][t] + sS[2][t] + sS[3][t];
}

__global__ void k_reduce_part(const float* __restrict__ part, int nblocks, float* __restrict__ small) {
    int c = blockIdx.x;   // 0..128 (128 == R)
    float acc = 0.f;
    for (int b = threadIdx.x; b < nblocks; b += blockDim.x) acc += part[b * 132 + c];
    __shared__ float sd[256];
    sd[threadIdx.x] = acc; __syncthreads();
    for (int off = 128; off; off >>= 1) { if (threadIdx.x < off) sd[threadIdx.x] += sd[threadIdx.x + off]; __syncthreads(); }
    if (threadIdx.x == 0) small[132 + c] = sd[0];
}

// ---------------- tail: newT = trainOT + (S@W2 + R*b2)@Wv + R*bv ----------------
__global__ void k_tiny2(const float* __restrict__ trainOT, const float* __restrict__ W2,
                        const float* __restrict__ b2, const float* __restrict__ Wv,
                        const float* __restrict__ bv, float* __restrict__ small,
                        float* __restrict__ out_tail) {
    __shared__ float t1[128];
    int t = threadIdx.x;   // 128
    float R = small[260];
    float acc = R * b2[t];
    for (int j = 0; j < 128; ++j) acc += small[132 + j] * W2[j * 128 + t];
    t1[t] = acc; __syncthreads();
    float acc2 = R * bv[t];
    for (int j = 0; j < 128; ++j) acc2 += t1[j] * Wv[j * 128 + t];
    float nt = trainOT[t] + acc2;
    small[264 + t] = nt;
    out_tail[t] = nt;
}

// ---------------- speak = newT @ Ws + bs (K split across 2 half-blocks) ----------------
__global__ void k_speak(const float* __restrict__ Ws, const float* __restrict__ bs,
                        const float* __restrict__ small, float* __restrict__ out, int out_n) {
    __shared__ float nt[128];
    __shared__ float s0[256], s1[256];
    int t = threadIdx.x;
    if (t < 128) nt[t] = small[264 + t];
    __syncthreads();
    int jj = (t & 127) * 2, kh = t >> 7;
    int j = blockIdx.x * 256 + jj;
    float acc0 = 0.f, acc1 = 0.f;
    if (j < out_n) {
        for (int k = kh * 64; k < kh * 64 + 64; ++k) {
            float w = nt[k];
            float2 r = *reinterpret_cast<const float2*>(Ws + (size_t)k * out_n + j);
            acc0 += w * r.x; acc1 += w * r.y;
        }
    }
    s0[t] = acc0; s1[t] = acc1; __syncthreads();
    if (t < 128 && j < out_n) {
        out[j]     = s0[t] + s0[t + 128] + bs[j];
        out[j + 1] = s1[t] + s1[t + 128] + bs[j + 1];
    }
}

extern "C" void kernel_launch(void* const* d_in, const int* in_sizes, int n_in,
                              void* d_out, int out_size, void* d_ws, size_t ws_size,
                              hipStream_t stream) {
    const float* features = (const float*)d_in[0];
    const int*   eidx     = (const int*)d_in[1];
    const float* trainOT  = (const float*)d_in[2];
    const float* W1 = (const float*)d_in[3];
    const float* b1 = (const float*)d_in[4];
    const float* W2 = (const float*)d_in[5];
    const float* b2 = (const float*)d_in[6];
    const float* Wq = (const float*)d_in[7];
    const float* bq = (const float*)d_in[8];
    const float* Wk = (const float*)d_in[9];
    const float* bk = (const float*)d_in[10];
    const float* Wv = (const float*)d_in[11];
    const float* bv = (const float*)d_in[12];
    const float* Ws = (const float*)d_in[13];
    const float* bs = (const float*)d_in[14];

    int N = in_sizes[0] / 3;
    int E = in_sizes[1] / 2;
    const int* esrc = eidx;
    const int* edst = eidx + E;

    char* ws = (char*)d_ws;
    int*   cnt     = (int*)(ws + O_CNT);
    int*   fill    = (int*)(ws + O_FILL);
    int*   row_ptr = (int*)(ws + O_ROWPTR);
    float* dinv    = (float*)(ws + O_DINV);
    float* small   = (float*)(ws + O_SMALL);
    float* xs      = (float*)(ws + O_XS);
    int*   col     = (int*)(ws + O_COL);
    float* part    = (float*)(ws + O_PART);
    unsigned int* h1s = (unsigned int*)(ws + O_H1);
    float* out     = (float*)d_out;
    int out_n = out_size - 128;

    hipMemsetAsync(cnt, 0, N * sizeof(int), stream);
    hipMemsetAsync(fill, 0, N * sizeof(int), stream);

    k_count<<<(E + 255) / 256, 256, 0, stream>>>(edst, cnt, E);
    k_prep<<<(N + 255) / 256, 256, 0, stream>>>(cnt, features, dinv, xs, N);
    k_scan<<<1, 1024, 0, stream>>>(cnt, row_ptr, N);
    k_fill<<<(E + 255) / 256, 256, 0, stream>>>(esrc, edst, row_ptr, fill, col, E);
    k_tiny1<<<1, 128, 0, stream>>>(trainOT, Wq, bq, Wk, bk, W2, b2, small);
    k_layer1<<<(N + 3) / 4, 256, 0, stream>>>(xs, row_ptr, col, dinv, W1, b1, h1s, N);
    k_layer2<<<LAYER2_BLOCKS, 256, 0, stream>>>(h1s, row_ptr, col, dinv, small, part, N);
    k_reduce_part<<<129, 256, 0, stream>>>(part, LAYER2_BLOCKS, small);
    k_tiny2<<<1, 128, 0, stream>>>(trainOT, W2, b2, Wv, bv, small, out + out_n);
    k_speak<<<(out_n + 255) / 256, 256, 0, stream>>>(Ws, bs, small, out, out_n);
}

// Round 3
// 197.593 us; speedup vs baseline: 1.4874x; 1.2559x over previous
//
#include <hip/hip_runtime.h>
#include <math.h>

// ---------------- workspace layout (bytes) ----------------
#define O_CNT    (0)                  // N ints (200KB)   -- cnt+fill zeroed by ONE memset
#define O_FILL   (256*1024)           // N ints (200KB)
#define O_ROWPTR (512*1024)           // N+1 ints
#define O_DINV   (768*1024)           // N floats
#define O_SMALL  (1024*1024)          // few KB
#define O_PART   (1536*1024)          // 2048*132*4 = 1.08MB
#define O_XS     (3*1024*1024)        // N float4 = 800KB
#define O_COL    (4*1024*1024)        // E ints = 3.2MB
#define O_H1     (8*1024*1024)        // (N+1)*64 uints (bf16x2) = 12.8MB + zero row
// small[] float indices:
//   [0..127] w2qk   [128] bias   [132..259] S   [260] R

#define LAYER2_BLOCKS 2048

static __device__ __forceinline__ unsigned int f2bf(float f) {
    unsigned int u = __float_as_uint(f);
    return (u + 0x7fffu + ((u >> 16) & 1u)) >> 16;            // RNE
}
static __device__ __forceinline__ float bf_lo(unsigned int w) { return __uint_as_float(w << 16); }
static __device__ __forceinline__ float bf_hi(unsigned int w) { return __uint_as_float(w & 0xffff0000u); }

// ---------------- CSR build ----------------
__global__ void k_count(const int* __restrict__ dst, int* __restrict__ cnt, int E) {
    int e = blockIdx.x * blockDim.x + threadIdx.x;
    if (e < E) atomicAdd(&cnt[dst[e]], 1);
}

// dinv + pre-scaled packed features xs4 = {x*dinv, pad}; also zero-row h1s[N]
__global__ void k_prep(const int* __restrict__ cnt, const float* __restrict__ x,
                       float* __restrict__ dinv, float4* __restrict__ xs4,
                       unsigned int* __restrict__ h1s, int N) {
    int i = blockIdx.x * blockDim.x + threadIdx.x;
    if (i < N) {
        float d = rsqrtf((float)(cnt[i] + 1));   // +1 self-loop
        dinv[i] = d;
        float4 v;
        v.x = x[i * 3] * d; v.y = x[i * 3 + 1] * d; v.z = x[i * 3 + 2] * d; v.w = 0.f;
        xs4[i] = v;
    }
    if (i < 64) h1s[(size_t)N * 64 + i] = 0u;    // zero row for ragged-tail gathers
}

static __device__ __forceinline__ int4 ld_cnt4(const int* __restrict__ cnt, int i, int N) {
    if (i + 3 < N) return *reinterpret_cast<const int4*>(cnt + i);
    int4 r;
    r.x = (i     < N) ? cnt[i]     : 0;
    r.y = (i + 1 < N) ? cnt[i + 1] : 0;
    r.z = (i + 2 < N) ? cnt[i + 2] : 0;
    r.w = (i + 3 < N) ? cnt[i + 3] : 0;
    return r;
}

// single-block scan: 1024 threads x 16 elems/thread per chunk (4 chunks @ N=50k)
__global__ void k_scan(const int* __restrict__ cnt, int* __restrict__ row_ptr, int N) {
    __shared__ int wsum[16];
    __shared__ int carry_s;
    __shared__ int tot_s;
    int t = threadIdx.x, lane = t & 63, wid = t >> 6;
    if (t == 0) { carry_s = 0; row_ptr[0] = 0; }
    __syncthreads();
    const int PER = 16, CHUNK = 1024 * PER;
    for (int base = 0; base < N; base += CHUNK) {
        int i0 = base + t * PER;
        int v[PER]; int s8 = 0;
#pragma unroll
        for (int k = 0; k < PER; k += 4) {
            int4 p = ld_cnt4(cnt, i0 + k, N);
            v[k] = p.x; v[k + 1] = p.y; v[k + 2] = p.z; v[k + 3] = p.w;
            s8 += p.x + p.y + p.z + p.w;
        }
        int incl = s8;
#pragma unroll
        for (int off = 1; off < 64; off <<= 1) {
            int n2 = __shfl_up(incl, off);
            if (lane >= off) incl += n2;
        }
        if (lane == 63) wsum[wid] = incl;
        __syncthreads();
        if (wid == 0) {
            int wv = (lane < 16) ? wsum[lane] : 0;
            int wincl = wv;
#pragma unroll
            for (int off = 1; off < 16; off <<= 1) {
                int n2 = __shfl_up(wincl, off);
                if (lane >= off) wincl += n2;
            }
            if (lane < 16) wsum[lane] = wincl - wv;   // exclusive
            if (lane == 15) tot_s = wincl;            // chunk total
        }
        __syncthreads();
        int run = carry_s + wsum[wid] + (incl - s8);
#pragma unroll
        for (int k = 0; k < PER; ++k) { int i = i0 + k; run += v[k]; if (i < N) row_ptr[i + 1] = run; }
        __syncthreads();
        if (t == 0) carry_s += tot_s;
        __syncthreads();
    }
}

__global__ void k_fill(const int* __restrict__ src, const int* __restrict__ dst,
                       const int* __restrict__ row_ptr, int* __restrict__ fill,
                       int* __restrict__ col, int E) {
    int e = blockIdx.x * blockDim.x + threadIdx.x;
    if (e < E) {
        int d = dst[e];
        int p = row_ptr[d] + atomicAdd(&fill[d], 1);
        col[p] = src[e];
    }
}

// ---------------- tiny precompute: w2qk / bias ----------------
__global__ void k_tiny1(const float* __restrict__ trainOT, const float* __restrict__ Wq,
                        const float* __restrict__ bq, const float* __restrict__ Wk,
                        const float* __restrict__ bk, const float* __restrict__ W2,
                        const float* __restrict__ b2, float* __restrict__ small) {
    __shared__ float kv[64];
    __shared__ float wqk[128];
    __shared__ float red[128];
    int t = threadIdx.x;   // 128 threads
    if (t < 64) {
        float acc = bk[t];
        for (int j = 0; j < 128; ++j) acc += trainOT[j] * Wk[j * 64 + t];
        kv[t] = acc;
    }
    __syncthreads();
    float accq = 0.f;
    for (int c = 0; c < 64; ++c) accq += Wq[t * 64 + c] * kv[c];
    wqk[t] = accq;
    red[t] = (t < 64) ? bq[t] * kv[t] : 0.f;
    __syncthreads();
    for (int off = 64; off >= 1; off >>= 1) { if (t < off) red[t] += red[t + off]; __syncthreads(); }
    float bqs = red[0];
    __syncthreads();
    float acc2 = 0.f;
    for (int j = 0; j < 128; ++j) acc2 += W2[t * 128 + j] * wqk[j];
    small[t] = acc2;                       // w2qk
    red[t] = b2[t] * wqk[t];
    __syncthreads();
    for (int off = 64; off >= 1; off >>= 1) { if (t < off) red[t] += red[t + off]; __syncthreads(); }
    if (t == 0) small[128] = bqs + red[0]; // bias
}

// ---------------- layer 1: 16 lanes/node; Agg(xs4) @W1+b1, relu, *dinv, pack bf16 ----------------
__global__ void k_layer1(const float4* __restrict__ xs4, const int* __restrict__ row_ptr,
                         const int* __restrict__ col, const float* __restrict__ dinv,
                         const float* __restrict__ W1, const float* __restrict__ b1,
                         unsigned int* __restrict__ h1s, int N) {
    int t = threadIdx.x;
    int sub = t & 15;
    int node = blockIdx.x * 16 + (t >> 4);        // 4 nodes per wave, 16 per block
    if (node >= N) return;
    float di = dinv[node];
    int s = row_ptr[node], e = row_ptr[node + 1];
    float a0 = 0.f, a1 = 0.f, a2 = 0.f;
    for (int j = s + sub; j < e; j += 16) {
        float4 xv = xs4[col[j]];
        a0 += xv.x; a1 += xv.y; a2 += xv.z;
    }
    if (sub == 0) { float4 xv = xs4[node]; a0 += xv.x; a1 += xv.y; a2 += xv.z; }
#pragma unroll
    for (int off = 1; off < 16; off <<= 1) {
        a0 += __shfl_xor(a0, off);
        a1 += __shfl_xor(a1, off);
        a2 += __shfl_xor(a2, off);
    }
    a0 *= di; a1 *= di; a2 *= di;
    unsigned int p[4];
#pragma unroll
    for (int m = 0; m < 4; ++m) {
        int c = 8 * sub + 2 * m;
        float vlo = fmaxf(a0 * W1[c]     + a1 * W1[128 + c]     + a2 * W1[256 + c]     + b1[c],     0.f) * di;
        float vhi = fmaxf(a0 * W1[c + 1] + a1 * W1[128 + c + 1] + a2 * W1[256 + c + 1] + b1[c + 1], 0.f) * di;
        p[m] = f2bf(vlo) | (f2bf(vhi) << 16);
    }
    uint4 st; st.x = p[0]; st.y = p[1]; st.z = p[2]; st.w = p[3];
    reinterpret_cast<uint4*>(h1s + (size_t)node * 64)[sub] = st;
}

// ---------------- layer 2 fused: quad-gather (4 edges per wave-load) ----------------
// g = Agg(h1s)*di; rel = sigmoid((g.w2qk+bias)/8); S += rel*g; R += rel
__global__ void k_layer2(const unsigned int* __restrict__ h1s, const int* __restrict__ row_ptr,
                         const int* __restrict__ col, const float* __restrict__ dinv,
                         const float* __restrict__ small, float* __restrict__ part, int N) {
    int t = threadIdx.x, lane = t & 63, wid = t >> 6;
    int sub = lane & 15, grp = lane >> 4;
    int wg = blockIdx.x * 4 + wid;
    const int nwaves = LAYER2_BLOCKS * 4;
    float w2[8];
#pragma unroll
    for (int j = 0; j < 8; ++j) w2[j] = small[8 * sub + j];
    float bias = small[128];
    float sacc[8];
#pragma unroll
    for (int j = 0; j < 8; ++j) sacc[j] = 0.f;
    float sR = 0.f;

    for (int node = wg; node < N; node += nwaves) {
        float di = dinv[node];
        int s = row_ptr[node], e = row_ptr[node + 1];
        int items = e - s + 1;                    // self + edges
        float acc[8];
#pragma unroll
        for (int j = 0; j < 8; ++j) acc[j] = 0.f;
        for (int base = 0; base < items; base += 8) {
            int q0 = base + grp, q1 = base + 4 + grp;
            int u0 = (q0 == 0) ? node : ((q0 < items) ? col[s + q0 - 1] : N);
            int u1 = (q1 < items) ? col[s + q1 - 1] : N;
            uint4 v0 = reinterpret_cast<const uint4*>(h1s + (size_t)u0 * 64)[sub];
            uint4 v1 = reinterpret_cast<const uint4*>(h1s + (size_t)u1 * 64)[sub];
            acc[0] += bf_lo(v0.x) + bf_lo(v1.x);
            acc[1] += bf_hi(v0.x) + bf_hi(v1.x);
            acc[2] += bf_lo(v0.y) + bf_lo(v1.y);
            acc[3] += bf_hi(v0.y) + bf_hi(v1.y);
            acc[4] += bf_lo(v0.z) + bf_lo(v1.z);
            acc[5] += bf_hi(v0.z) + bf_hi(v1.z);
            acc[6] += bf_lo(v0.w) + bf_lo(v1.w);
            acc[7] += bf_hi(v0.w) + bf_hi(v1.w);
        }
        // reduce across the 4 groups (lanes ^16, ^32)
#pragma unroll
        for (int j = 0; j < 8; ++j) {
            acc[j] += __shfl_xor(acc[j], 16);
            acc[j] += __shfl_xor(acc[j], 32);
        }
        float dv = 0.f;
#pragma unroll
        for (int j = 0; j < 8; ++j) dv += acc[j] * w2[j];
#pragma unroll
        for (int off = 1; off < 16; off <<= 1) dv += __shfl_xor(dv, off);
        float z = (dv * di + bias) * 0.125f;      // / sqrt(64)
        float rel = 1.f / (1.f + __expf(-z));
        float rd = rel * di;
#pragma unroll
        for (int j = 0; j < 8; ++j) sacc[j] += rd * acc[j];
        sR += rel;
    }
    __shared__ float sS[4][132];
    if (grp == 0) {
#pragma unroll
        for (int j = 0; j < 8; ++j) sS[wid][8 * sub + j] = sacc[j];
    }
    if (lane == 0) sS[wid][128] = sR;
    __syncthreads();
    if (t < 129) part[blockIdx.x * 132 + t] = sS[0][t] + sS[1][t] + sS[2][t] + sS[3][t];
}

__global__ void k_reduce_part(const float* __restrict__ part, int nblocks, float* __restrict__ small) {
    int c = blockIdx.x;   // 0..128 (128 == R)
    float acc = 0.f;
    for (int b = threadIdx.x; b < nblocks; b += blockDim.x) acc += part[b * 132 + c];
    __shared__ float sd[256];
    sd[threadIdx.x] = acc; __syncthreads();
    for (int off = 128; off; off >>= 1) { if (threadIdx.x < off) sd[threadIdx.x] += sd[threadIdx.x + off]; __syncthreads(); }
    if (threadIdx.x == 0) small[132 + c] = sd[0];
}

// ---------------- tail fused: newT = trainOT + (S@W2 + R*b2)@Wv + R*bv; out = newT@Ws + bs ----------------
__global__ void k_tail(const float* __restrict__ trainOT, const float* __restrict__ W2,
                       const float* __restrict__ b2, const float* __restrict__ Wv,
                       const float* __restrict__ bv, const float* __restrict__ Ws,
                       const float* __restrict__ bs, const float* __restrict__ small,
                       float* __restrict__ out, int out_n) {
    __shared__ float t1[128];
    __shared__ float nt[128];
    __shared__ float s0[256], s1[256];
    int t = threadIdx.x;   // 256
    float R = small[260];
    if (t < 128) {
        float acc = R * b2[t];
        for (int j = 0; j < 128; ++j) acc += small[132 + j] * W2[j * 128 + t];
        t1[t] = acc;
    }
    __syncthreads();
    if (t < 128) {
        float acc2 = R * bv[t];
        for (int j = 0; j < 128; ++j) acc2 += t1[j] * Wv[j * 128 + t];
        nt[t] = trainOT[t] + acc2;
    }
    __syncthreads();
    if (blockIdx.x == 0 && t < 128) out[out_n + t] = nt[t];   // new_trainOT output

    int jj = (t & 127) * 2, kh = t >> 7;
    int j = blockIdx.x * 256 + jj;
    float acc0 = 0.f, acc1 = 0.f;
    if (j < out_n) {
        for (int k = kh * 64; k < kh * 64 + 64; ++k) {
            float w = nt[k];
            float2 r = *reinterpret_cast<const float2*>(Ws + (size_t)k * out_n + j);
            acc0 += w * r.x; acc1 += w * r.y;
        }
    }
    s0[t] = acc0; s1[t] = acc1; __syncthreads();
    if (t < 128 && j < out_n) {
        out[j]     = s0[t] + s0[t + 128] + bs[j];
        out[j + 1] = s1[t] + s1[t + 128] + bs[j + 1];
    }
}

extern "C" void kernel_launch(void* const* d_in, const int* in_sizes, int n_in,
                              void* d_out, int out_size, void* d_ws, size_t ws_size,
                              hipStream_t stream) {
    const float* features = (const float*)d_in[0];
    const int*   eidx     = (const int*)d_in[1];
    const float* trainOT  = (const float*)d_in[2];
    const float* W1 = (const float*)d_in[3];
    const float* b1 = (const float*)d_in[4];
    const float* W2 = (const float*)d_in[5];
    const float* b2 = (const float*)d_in[6];
    const float* Wq = (const float*)d_in[7];
    const float* bq = (const float*)d_in[8];
    const float* Wk = (const float*)d_in[9];
    const float* bk = (const float*)d_in[10];
    const float* Wv = (const float*)d_in[11];
    const float* bv = (const float*)d_in[12];
    const float* Ws = (const float*)d_in[13];
    const float* bs = (const float*)d_in[14];

    int N = in_sizes[0] / 3;
    int E = in_sizes[1] / 2;
    const int* esrc = eidx;
    const int* edst = eidx + E;

    char* ws = (char*)d_ws;
    int*   cnt     = (int*)(ws + O_CNT);
    int*   fill    = (int*)(ws + O_FILL);
    int*   row_ptr = (int*)(ws + O_ROWPTR);
    float* dinv    = (float*)(ws + O_DINV);
    float* small   = (float*)(ws + O_SMALL);
    float* part    = (float*)(ws + O_PART);
    float4* xs4    = (float4*)(ws + O_XS);
    int*   col     = (int*)(ws + O_COL);
    unsigned int* h1s = (unsigned int*)(ws + O_H1);
    float* out     = (float*)d_out;
    int out_n = out_size - 128;

    hipMemsetAsync(ws, 0, O_FILL + 256 * 1024, stream);   // cnt + fill in one shot

    k_tiny1<<<1, 128, 0, stream>>>(trainOT, Wq, bq, Wk, bk, W2, b2, small);
    k_count<<<(E + 255) / 256, 256, 0, stream>>>(edst, cnt, E);
    k_prep<<<(N + 255) / 256, 256, 0, stream>>>(cnt, features, dinv, xs4, h1s, N);
    k_scan<<<1, 1024, 0, stream>>>(cnt, row_ptr, N);
    k_fill<<<(E + 255) / 256, 256, 0, stream>>>(esrc, edst, row_ptr, fill, col, E);
    k_layer1<<<(N + 15) / 16, 256, 0, stream>>>(xs4, row_ptr, col, dinv, W1, b1, h1s, N);
    k_layer2<<<LAYER2_BLOCKS, 256, 0, stream>>>(h1s, row_ptr, col, dinv, small, part, N);
    k_reduce_part<<<129, 256, 0, stream>>>(part, LAYER2_BLOCKS, small);
    k_tail<<<(out_n + 255) / 256, 256, 0, stream>>>(trainOT, W2, b2, Wv, bv, Ws, bs, small, out, out_n);
}